// Round 1
// baseline (228.467 us; speedup 1.0000x reference)
//
#include <hip/hip_runtime.h>

#define IMG_H 512
#define IMG_W 512
#define RH 32   // output rows per block; 34 input rows read (1.0625x halo overfetch)

__global__ void ssim_init_kernel(double* __restrict__ accum) {
    if (threadIdx.x == 0 && blockIdx.x == 0) *accum = 0.0;
}

// One block: 256 threads, plane blockIdx.y, rows [blockIdx.x*RH, +RH), full 512 width.
// Thread t owns columns 2t, 2t+1. Row-at-a-time: double-buffered LDS row staging
// (1 barrier/row, global prefetch of next row issued before the barrier),
// separable 3-tap conv via a 3-row rolling register window of the 5 horizontal sums.
__global__ __launch_bounds__(256) void ssim_main_kernel(
    const float* __restrict__ img1, const float* __restrict__ img2,
    double* __restrict__ accum)
{
    // f32-rounded Gaussian(sigma=1.5, k=3) weights, matching JAX's f32 computation
    constexpr float W_E = 0.30780133f;  // exp(-1/4.5)/(1+2exp(-1/4.5))
    constexpr float W_C = 0.38439734f;  // 1/(1+2exp(-1/4.5))
    constexpr float C1 = 1e-4f;
    constexpr float C2 = 9e-4f;

    const int t = threadIdx.x;
    const int y0 = blockIdx.x * RH;
    const size_t base = (size_t)blockIdx.y * (IMG_H * IMG_W);
    const float* __restrict__ A = img1 + base;
    const float* __restrict__ B = img2 + base;

    // 514 used columns (+zero borders at [0] and [513]); 520 stride keeps float2 alignment
    __shared__ __align__(16) float lsA[2][520];
    __shared__ __align__(16) float lsB[2][520];
    if (t < 2) {
        lsA[0][t * 513] = 0.0f; lsA[1][t * 513] = 0.0f;
        lsB[0][t * 513] = 0.0f; lsB[1][t * 513] = 0.0f;
    }

    const int x = 2 * t;  // owned columns x, x+1

    // rolling window [row-2, row-1, row] of horizontal conv sums, per column
    float h1[2][3], h2[2][3], h11[2][3], h22[2][3], h12[2][3];
#pragma unroll
    for (int c = 0; c < 2; ++c)
#pragma unroll
        for (int r = 0; r < 3; ++r) {
            h1[c][r] = 0.f; h2[c][r] = 0.f;
            h11[c][r] = 0.f; h22[c][r] = 0.f; h12[c][r] = 0.f;
        }

    // prologue: prefetch input row y0-1 (zeros if above the image)
    float2 pa = make_float2(0.f, 0.f), pb = make_float2(0.f, 0.f);
    {
        const int yi = y0 - 1;
        if (yi >= 0) {
            pa = *(const float2*)(A + (size_t)yi * IMG_W + x);
            pb = *(const float2*)(B + (size_t)yi * IMG_W + x);
        }
    }

    float tsum = 0.0f;

    for (int i = 0; i < RH + 2; ++i) {   // input row yi = y0 - 1 + i
        const int buf = i & 1;
        lsA[buf][1 + x] = pa.x; lsA[buf][2 + x] = pa.y;
        lsB[buf][1 + x] = pb.x; lsB[buf][2 + x] = pb.y;

        // prefetch next input row (issued before the barrier; consumed next iter)
        const int yn = y0 + i;  // = (y0-1) + (i+1)
        float2 na = make_float2(0.f, 0.f), nb = make_float2(0.f, 0.f);
        if (i + 1 < RH + 2 && yn < IMG_H) {
            na = *(const float2*)(A + (size_t)yn * IMG_W + x);
            nb = *(const float2*)(B + (size_t)yn * IMG_W + x);
        }

        __syncthreads();  // writes of buf visible; also fences reuse of buf^1 (double buffer)

        // neighborhood cols x-1..x+2 live at LDS indices x..x+3 (border offset +1)
        const float2 a01 = *(const float2*)&lsA[buf][x];
        const float2 a23 = *(const float2*)&lsA[buf][x + 2];
        const float2 b01 = *(const float2*)&lsB[buf][x];
        const float2 b23 = *(const float2*)&lsB[buf][x + 2];
        const float av[4] = {a01.x, a01.y, a23.x, a23.y};
        const float bv[4] = {b01.x, b01.y, b23.x, b23.y};

#pragma unroll
        for (int c = 0; c < 2; ++c) {
            h1[c][0] = h1[c][1];  h1[c][1] = h1[c][2];
            h2[c][0] = h2[c][1];  h2[c][1] = h2[c][2];
            h11[c][0] = h11[c][1]; h11[c][1] = h11[c][2];
            h22[c][0] = h22[c][1]; h22[c][1] = h22[c][2];
            h12[c][0] = h12[c][1]; h12[c][1] = h12[c][2];
            const float am = av[c], a0 = av[c + 1], ap = av[c + 2];
            const float bm = bv[c], b0 = bv[c + 1], bp = bv[c + 2];
            h1[c][2]  = W_E * (am + ap) + W_C * a0;
            h2[c][2]  = W_E * (bm + bp) + W_C * b0;
            h11[c][2] = W_E * (am * am + ap * ap) + W_C * (a0 * a0);
            h22[c][2] = W_E * (bm * bm + bp * bp) + W_C * (b0 * b0);
            h12[c][2] = W_E * (am * bm + ap * bp) + W_C * (a0 * b0);
        }

        if (i >= 2) {  // output row yo = yi-1 ready
#pragma unroll
            for (int c = 0; c < 2; ++c) {
                const float mu1 = W_E * (h1[c][0] + h1[c][2]) + W_C * h1[c][1];
                const float mu2 = W_E * (h2[c][0] + h2[c][2]) + W_C * h2[c][1];
                const float e11 = W_E * (h11[c][0] + h11[c][2]) + W_C * h11[c][1];
                const float e22 = W_E * (h22[c][0] + h22[c][2]) + W_C * h22[c][1];
                const float e12 = W_E * (h12[c][0] + h12[c][2]) + W_C * h12[c][1];
                const float mu1s = mu1 * mu1, mu2s = mu2 * mu2, m12 = mu1 * mu2;
                const float s11 = e11 - mu1s, s22 = e22 - mu2s, s12 = e12 - m12;
                const float num = (2.0f * m12 + C1) * (2.0f * s12 + C2);
                const float den = (mu1s + mu2s + C1) * (s11 + s22 + C2);
                tsum += num / den;
            }
        }

        pa = na; pb = nb;
    }

    // 64-lane wave reduction
#pragma unroll
    for (int off = 32; off >= 1; off >>= 1)
        tsum += __shfl_xor(tsum, off, 64);

    __shared__ float wpart[4];
    if ((t & 63) == 0) wpart[t >> 6] = tsum;
    __syncthreads();
    if (t == 0) {
        const double bs = (double)wpart[0] + (double)wpart[1] +
                          (double)wpart[2] + (double)wpart[3];
        atomicAdd(accum, bs);  // 1536 atomics total; CAS fallback is fine
    }
}

__global__ void ssim_fin_kernel(const double* __restrict__ accum,
                                float* __restrict__ out) {
    if (threadIdx.x == 0 && blockIdx.x == 0) out[0] = 1.0f - (float)(*accum);
}

extern "C" void kernel_launch(void* const* d_in, const int* in_sizes, int n_in,
                              void* d_out, int out_size, void* d_ws, size_t ws_size,
                              hipStream_t stream) {
    const float* img1 = (const float*)d_in[0];
    const float* img2 = (const float*)d_in[1];
    float* out = (float*)d_out;
    double* accum = (double*)d_ws;

    const int planes = in_sizes[0] / (IMG_H * IMG_W);  // 32*3 = 96

    ssim_init_kernel<<<1, 1, 0, stream>>>(accum);
    dim3 grid(IMG_H / RH, planes);
    ssim_main_kernel<<<grid, 256, 0, stream>>>(img1, img2, accum);
    ssim_fin_kernel<<<1, 1, 0, stream>>>(accum, out);
}